// Round 1
// baseline (244.228 us; speedup 1.0000x reference)
//
#include <hip/hip_runtime.h>
#include <hip/hip_bf16.h>
#include <stdint.h>

// Problem constants: B=4, N=4096, D=1024, H=16, M=256, DH=64
#define DATA_SCALE 0.35355339059327373f  // 64^-0.25
#define DN_SCALE   0.0625f               // 0.5 * 64^-0.5

typedef __bf16 bf16x8 __attribute__((ext_vector_type(8)));
typedef float  f32x4  __attribute__((ext_vector_type(4)));

static __device__ __forceinline__ unsigned short f2bf(float f) {
    union { float f; unsigned int u; } v; v.f = f;
    unsigned int r = v.u + 0x7fffu + ((v.u >> 16) & 1u);
    return (unsigned short)(r >> 16);
}

static __device__ __forceinline__ f32x4 mfma16(bf16x8 a, bf16x8 b, f32x4 c) {
    return __builtin_amdgcn_mfma_f32_16x16x32_bf16(a, b, c, 0, 0, 0);
}

// ---------------------------------------------------------------- prep ----
__global__ __launch_bounds__(256) void k_prep(const float* __restrict__ W,
                                              const float* __restrict__ proj,
                                              unsigned short* __restrict__ Wb,
                                              unsigned short* __restrict__ projs) {
    int i = blockIdx.x * 256 + threadIdx.x;
    if (i < 1024 * 1024) Wb[i] = f2bf(W[i]);
    if (i < 256 * 64)    projs[i] = f2bf(proj[i] * DATA_SCALE);
}

// ------------------------------------------------------------- k_ctx ------
// grid = 64 bh * 4 chunks; block 256.  Computes ctx_part[bh][chunk][m][dh]
// and ksum_part[bh][chunk][m] over 1024 rows per chunk (16 tiles of 64).
__global__ __launch_bounds__(256) void k_ctx(const float* __restrict__ kg,
                                             const float* __restrict__ vg,
                                             const unsigned short* __restrict__ projs,
                                             float* __restrict__ ctx_part,
                                             float* __restrict__ ksum_part) {
    const int bh = blockIdx.x >> 2, chunk = blockIdx.x & 3;
    const int b = bh >> 4, h = bh & 15;
    const int tid = threadIdx.x;
    const int w = tid >> 6, lane = tid & 63, l15 = lane & 15, hh = lane >> 4;

    __shared__ __align__(16) unsigned short Kt[64][72];
    __shared__ __align__(16) unsigned short VT[64][72];
    __shared__ __align__(16) unsigned short kpT[256][72];
    __shared__ float dnp[64][4];
    __shared__ float rmW[4][64];
    __shared__ float offs[64];

    // hoist proj B-fragments (loop invariant): wave w owns m in [64w,64w+64)
    bf16x8 pb[4][2];
#pragma unroll
    for (int ni = 0; ni < 4; ++ni)
#pragma unroll
        for (int ks = 0; ks < 2; ++ks)
            pb[ni][ks] = *(const bf16x8*)(projs + (size_t)(64*w + 16*ni + l15) * 64 + ks*32 + 8*hh);

    f32x4 cacc[4][4];
#pragma unroll
    for (int i = 0; i < 4; ++i)
#pragma unroll
        for (int j = 0; j < 4; ++j) cacc[i][j] = (f32x4){0.f, 0.f, 0.f, 0.f};
    float ksacc[4] = {0.f, 0.f, 0.f, 0.f};

    const size_t rowoff = (size_t)(b * 4096 + chunk * 1024) * 1024 + h * 64;

    for (int tt = 0; tt < 16; ++tt) {
        __syncthreads();
        // ---- stage K tile (+ per-row sum of squares), rows tt*64..+63 ----
        {
            const int r = tid >> 2, q = tid & 3;
            const float* src = kg + rowoff + (size_t)(tt*64 + r) * 1024 + q * 16;
            float s2 = 0.f;
            union { unsigned short s[16]; uint4 v4[2]; } tmp;
#pragma unroll
            for (int j = 0; j < 16; j += 4) {
                float4 f = *(const float4*)(src + j);
                s2 += f.x*f.x + f.y*f.y + f.z*f.z + f.w*f.w;
                tmp.s[j+0] = f2bf(f.x); tmp.s[j+1] = f2bf(f.y);
                tmp.s[j+2] = f2bf(f.z); tmp.s[j+3] = f2bf(f.w);
            }
            *(uint4*)&Kt[r][q*16]     = tmp.v4[0];
            *(uint4*)&Kt[r][q*16 + 8] = tmp.v4[1];
            dnp[r][q] = s2;
        }
        // ---- stage V transposed: VT[dh][n] ----
        {
            const int n = lane, cs = w * 16;
            const float* src = vg + rowoff + (size_t)(tt*64 + n) * 1024 + cs;
#pragma unroll
            for (int j = 0; j < 16; j += 4) {
                float4 f = *(const float4*)(src + j);
                VT[cs+j+0][n] = f2bf(f.x); VT[cs+j+1][n] = f2bf(f.y);
                VT[cs+j+2][n] = f2bf(f.z); VT[cs+j+3][n] = f2bf(f.w);
            }
        }
        __syncthreads();

        // ---- S = Ktile @ projs^T  (wave w -> m slice 64w..64w+63) ----
        f32x4 sacc[4][4];
#pragma unroll
        for (int i = 0; i < 4; ++i)
#pragma unroll
            for (int j = 0; j < 4; ++j) sacc[i][j] = (f32x4){0.f, 0.f, 0.f, 0.f};
#pragma unroll
        for (int ks = 0; ks < 2; ++ks) {
            bf16x8 af[4];
#pragma unroll
            for (int mi = 0; mi < 4; ++mi)
                af[mi] = *(const bf16x8*)&Kt[16*mi + l15][ks*32 + 8*hh];
#pragma unroll
            for (int mi = 0; mi < 4; ++mi)
#pragma unroll
                for (int ni = 0; ni < 4; ++ni)
                    sacc[mi][ni] = mfma16(af[mi], pb[ni][ks], sacc[mi][ni]);
        }

        // ---- per-row max over m (k-side): in-reg + shfl + cross-wave LDS --
        float pm[4][4];
#pragma unroll
        for (int mi = 0; mi < 4; ++mi)
#pragma unroll
            for (int r = 0; r < 4; ++r)
                pm[mi][r] = fmaxf(fmaxf(sacc[mi][0][r], sacc[mi][1][r]),
                                  fmaxf(sacc[mi][2][r], sacc[mi][3][r]));
#pragma unroll
        for (int msk = 1; msk <= 8; msk <<= 1)
#pragma unroll
            for (int mi = 0; mi < 4; ++mi)
#pragma unroll
                for (int r = 0; r < 4; ++r)
                    pm[mi][r] = fmaxf(pm[mi][r], __shfl_xor(pm[mi][r], msk));
        if (l15 == 0) {
#pragma unroll
            for (int mi = 0; mi < 4; ++mi)
#pragma unroll
                for (int r = 0; r < 4; ++r)
                    rmW[w][16*mi + 4*hh + r] = pm[mi][r];
        }
        __syncthreads();
        if (tid < 64) {
            float m0 = fmaxf(fmaxf(rmW[0][tid], rmW[1][tid]),
                             fmaxf(rmW[2][tid], rmW[3][tid]));
            float dn = DN_SCALE * (dnp[tid][0] + dnp[tid][1] + dnp[tid][2] + dnp[tid][3]);
            offs[tid] = m0 + dn;
        }
        __syncthreads();

        // ---- kp = exp(S - off[n]); pack transposed kpT[m][n]; ksum acc ----
#pragma unroll
        for (int mi = 0; mi < 4; ++mi) {
            float ov[4];
#pragma unroll
            for (int r = 0; r < 4; ++r) ov[r] = offs[16*mi + 4*hh + r];
#pragma unroll
            for (int ni = 0; ni < 4; ++ni) {
                const int m = 64*w + 16*ni + l15;
                unsigned int p0, p1;
                {
                    float e0 = __expf(sacc[mi][ni][0] - ov[0]);
                    float e1 = __expf(sacc[mi][ni][1] - ov[1]);
                    float e2 = __expf(sacc[mi][ni][2] - ov[2]);
                    float e3 = __expf(sacc[mi][ni][3] - ov[3]);
                    ksacc[ni] += e0 + e1 + e2 + e3;
                    p0 = (unsigned int)f2bf(e0) | ((unsigned int)f2bf(e1) << 16);
                    p1 = (unsigned int)f2bf(e2) | ((unsigned int)f2bf(e3) << 16);
                }
                uint2 pk; pk.x = p0; pk.y = p1;
                *(uint2*)&kpT[m][16*mi + 4*hh] = pk;
            }
        }

        // ---- ctx += kp^T @ V  (contraction over this tile's 64 rows) ----
#pragma unroll
        for (int ns = 0; ns < 2; ++ns) {
            bf16x8 am[4], bv[4];
#pragma unroll
            for (int mi = 0; mi < 4; ++mi)
                am[mi] = *(const bf16x8*)&kpT[64*w + 16*mi + l15][ns*32 + 8*hh];
#pragma unroll
            for (int ni = 0; ni < 4; ++ni)
                bv[ni] = *(const bf16x8*)&VT[16*ni + l15][ns*32 + 8*hh];
#pragma unroll
            for (int mi = 0; mi < 4; ++mi)
#pragma unroll
                for (int ni = 0; ni < 4; ++ni)
                    cacc[mi][ni] = mfma16(am[mi], bv[ni], cacc[mi][ni]);
        }
    }

    // ---- epilogue: partial ksum + partial ctx ----
#pragma unroll
    for (int ni = 0; ni < 4; ++ni) {
        ksacc[ni] += __shfl_xor(ksacc[ni], 16);
        ksacc[ni] += __shfl_xor(ksacc[ni], 32);
    }
    const int pc = bh * 4 + chunk;
    if (hh == 0) {
#pragma unroll
        for (int ni = 0; ni < 4; ++ni)
            ksum_part[(size_t)pc * 256 + 64*w + 16*ni + l15] = ksacc[ni];
    }
    float* cp = ctx_part + (size_t)pc * 256 * 64;
#pragma unroll
    for (int mi = 0; mi < 4; ++mi)
#pragma unroll
        for (int ni = 0; ni < 4; ++ni)
#pragma unroll
            for (int r = 0; r < 4; ++r)
                cp[(64*w + 16*mi + 4*hh + r) * 64 + 16*ni + l15] = cacc[mi][ni][r];
}

// ------------------------------------------------------------ reduce ------
// grid = 64 (bh); block 256.  ctxT[bh][dh][m] bf16, ksum[bh][m] f32.
__global__ __launch_bounds__(256) void k_reduce(const float* __restrict__ ctx_part,
                                                const float* __restrict__ ksum_part,
                                                unsigned short* __restrict__ ctxT,
                                                float* __restrict__ ksum) {
    const int bh = blockIdx.x, t = threadIdx.x;
    const float* cp = ctx_part + (size_t)bh * 4 * 16384;
    unsigned short* ct = ctxT + (size_t)bh * 16384;
#pragma unroll 4
    for (int dh = 0; dh < 64; ++dh) {
        float s = cp[t*64 + dh] + cp[16384 + t*64 + dh]
                + cp[2*16384 + t*64 + dh] + cp[3*16384 + t*64 + dh];
        ct[dh * 256 + t] = f2bf(s);
    }
    const float* kp_ = ksum_part + (size_t)bh * 4 * 256;
    ksum[(size_t)bh * 256 + t] = kp_[t] + kp_[256 + t] + kp_[512 + t] + kp_[768 + t];
}

// ------------------------------------------------------------- k_qout -----
// grid = 64 bh * 16 rowgroups (256 rows each); block 256.
__global__ __launch_bounds__(256) void k_qout(const float* __restrict__ qg,
                                              const unsigned short* __restrict__ projs,
                                              const unsigned short* __restrict__ ctxT,
                                              const float* __restrict__ ksum,
                                              unsigned short* __restrict__ attn) {
    const int bh = blockIdx.x >> 4, rg = blockIdx.x & 15;
    const int b = bh >> 4, h = bh & 15;
    const int tid = threadIdx.x;
    const int w = tid >> 6, lane = tid & 63, l15 = lane & 15, hh = lane >> 4;

    __shared__ __align__(16) unsigned short Qt[64][72];
    __shared__ __align__(16) unsigned short uL[64][264];
    __shared__ float denW[4][64];
    __shared__ float rden[64];

    bf16x8 pb[4][2];
#pragma unroll
    for (int ni = 0; ni < 4; ++ni)
#pragma unroll
        for (int ks = 0; ks < 2; ++ks)
            pb[ni][ks] = *(const bf16x8*)(projs + (size_t)(64*w + 16*ni + l15) * 64 + ks*32 + 8*hh);

    float ksr[4];   // ksum values for this lane's m columns (f32, exact)
#pragma unroll
    for (int ni = 0; ni < 4; ++ni)
        ksr[ni] = ksum[(size_t)bh * 256 + 64*w + 16*ni + l15];

    const unsigned short* cb = ctxT + (size_t)bh * 16384;
    const size_t qrowoff = (size_t)(b * 4096 + rg * 256) * 1024 + h * 64;

    for (int t4 = 0; t4 < 4; ++t4) {
        if (t4) __syncthreads();
        // ---- stage Q tile ----
        {
            const int r = tid >> 2, q = tid & 3;
            const float* src = qg + qrowoff + (size_t)(t4*64 + r) * 1024 + q * 16;
            union { unsigned short s[16]; uint4 v4[2]; } tmp;
#pragma unroll
            for (int j = 0; j < 16; j += 4) {
                float4 f = *(const float4*)(src + j);
                tmp.s[j+0] = f2bf(f.x); tmp.s[j+1] = f2bf(f.y);
                tmp.s[j+2] = f2bf(f.z); tmp.s[j+3] = f2bf(f.w);
            }
            *(uint4*)&Qt[r][q*16]     = tmp.v4[0];
            *(uint4*)&Qt[r][q*16 + 8] = tmp.v4[1];
        }
        __syncthreads();

        // ---- S_q GEMM ----
        f32x4 sacc[4][4];
#pragma unroll
        for (int i = 0; i < 4; ++i)
#pragma unroll
            for (int j = 0; j < 4; ++j) sacc[i][j] = (f32x4){0.f, 0.f, 0.f, 0.f};
#pragma unroll
        for (int ks = 0; ks < 2; ++ks) {
            bf16x8 af[4];
#pragma unroll
            for (int mi = 0; mi < 4; ++mi)
                af[mi] = *(const bf16x8*)&Qt[16*mi + l15][ks*32 + 8*hh];
#pragma unroll
            for (int mi = 0; mi < 4; ++mi)
#pragma unroll
                for (int ni = 0; ni < 4; ++ni)
                    sacc[mi][ni] = mfma16(af[mi], pb[ni][ks], sacc[mi][ni]);
        }

        // ---- u = exp(S) (no offsets needed: per-row factors cancel) ----
        float dp[4][4];  // per-lane den partials for rows n=16mi+4hh+r
#pragma unroll
        for (int mi = 0; mi < 4; ++mi)
#pragma unroll
            for (int r = 0; r < 4; ++r) dp[mi][r] = 0.f;
#pragma unroll
        for (int mi = 0; mi < 4; ++mi)
#pragma unroll
            for (int ni = 0; ni < 4; ++ni) {
                const int m = 64*w + 16*ni + l15;
#pragma unroll
                for (int r = 0; r < 4; ++r) {
                    float e = __expf(sacc[mi][ni][r]);
                    dp[mi][r] += e * ksr[ni];
                    uL[16*mi + 4*hh + r][m] = f2bf(e);
                }
            }
        // reduce den over the 16-lane group (covers this wave's 64 m)
#pragma unroll
        for (int msk = 1; msk <= 8; msk <<= 1)
#pragma unroll
            for (int mi = 0; mi < 4; ++mi)
#pragma unroll
                for (int r = 0; r < 4; ++r)
                    dp[mi][r] += __shfl_xor(dp[mi][r], msk);
        if (l15 == 0) {
#pragma unroll
            for (int mi = 0; mi < 4; ++mi)
#pragma unroll
                for (int r = 0; r < 4; ++r)
                    denW[w][16*mi + 4*hh + r] = dp[mi][r];
        }
        __syncthreads();
        if (tid < 64)
            rden[tid] = 1.f / (denW[0][tid] + denW[1][tid] + denW[2][tid] + denW[3][tid]);
        __syncthreads();

        // ---- num = u @ ctx : wave w computes rows [16w,16w+16) ----
        f32x4 nacc[4];
#pragma unroll
        for (int i = 0; i < 4; ++i) nacc[i] = (f32x4){0.f, 0.f, 0.f, 0.f};
#pragma unroll
        for (int ks = 0; ks < 8; ++ks) {
            bf16x8 a = *(const bf16x8*)&uL[16*w + l15][ks*32 + 8*hh];
#pragma unroll
            for (int ni = 0; ni < 4; ++ni) {
                bf16x8 bb = *(const bf16x8*)(cb + (size_t)(16*ni + l15) * 256 + ks*32 + 8*hh);
                nacc[ni] = mfma16(a, bb, nacc[ni]);
            }
        }

        // ---- epilogue: attn[b][n][h*64+dh] = num/den (bf16) ----
#pragma unroll
        for (int r = 0; r < 4; ++r) {
            const int nloc = 16*w + 4*hh + r;
            const float rd = rden[nloc];
            const int grow = rg*256 + t4*64 + nloc;
            unsigned short* dst = attn + (size_t)(b*4096 + grow) * 1024 + h*64;
#pragma unroll
            for (int ni = 0; ni < 4; ++ni)
                dst[16*ni + l15] = f2bf(nacc[ni][r] * rd);
        }
    }
}

// ------------------------------------------------------------ k_linear ----
// out[16384][1024] = attn_bf16 @ Wb^T + bias  (NT GEMM, 128x128x32 tiles)
__global__ __launch_bounds__(256) void k_linear(const unsigned short* __restrict__ A,
                                                const unsigned short* __restrict__ Wb,
                                                const float* __restrict__ bias,
                                                float* __restrict__ out) {
    const int bm = blockIdx.x >> 3, bn = blockIdx.x & 7;
    const int tid = threadIdx.x;
    const int w = tid >> 6, lane = tid & 63, l15 = lane & 15, hh = lane >> 4;
    const int wm = w >> 1, wn = w & 1;
    const int m0 = bm * 128, n0 = bn * 128;

    __shared__ __align__(16) unsigned short As[128][40];
    __shared__ __align__(16) unsigned short Bs[128][40];

    const int sr = tid >> 2, sq = tid & 3;
    const unsigned short* Ag = A  + (size_t)(m0 + sr) * 1024 + sq * 8;
    const unsigned short* Bg = Wb + (size_t)(n0 + sr) * 1024 + sq * 8;

    f32x4 acc[4][4];
#pragma unroll
    for (int i = 0; i < 4; ++i)
#pragma unroll
        for (int j = 0; j < 4; ++j) acc[i][j] = (f32x4){0.f, 0.f, 0.f, 0.f};

    uint4 ra0, ra1, rb0, rb1;
    ra0 = *(const uint4*)(Ag);
    ra1 = *(const uint4*)(Ag + 64*1024);
    rb0 = *(const uint4*)(Bg);
    rb1 = *(const uint4*)(Bg + 64*1024);

#pragma unroll 1
    for (int kt = 0; kt < 32; ++kt) {
        __syncthreads();
        *(uint4*)&As[sr][sq*8]      = ra0;
        *(uint4*)&As[64 + sr][sq*8] = ra1;
        *(uint4*)&Bs[sr][sq*8]      = rb0;
        *(uint4*)&Bs[64 + sr][sq*8] = rb1;
        __syncthreads();
        if (kt < 31) {
            ra0 = *(const uint4*)(Ag + (size_t)(kt+1)*32);
            ra1 = *(const uint4*)(Ag + 64*1024 + (size_t)(kt+1)*32);
            rb0 = *(const uint4*)(Bg + (size_t)(kt+1)*32);
            rb1 = *(const uint4*)(Bg + 64*1024 + (size_t)(kt+1)*32);
        }
        bf16x8 af[4], bw[4];
#pragma unroll
        for (int mi = 0; mi < 4; ++mi)
            af[mi] = *(const bf16x8*)&As[wm*64 + 16*mi + l15][8*hh];
#pragma unroll
        for (int ni = 0; ni < 4; ++ni)
            bw[ni] = *(const bf16x8*)&Bs[wn*64 + 16*ni + l15][8*hh];
#pragma unroll
        for (int mi = 0; mi < 4; ++mi)
#pragma unroll
            for (int ni = 0; ni < 4; ++ni)
                acc[mi][ni] = mfma16(af[mi], bw[ni], acc[mi][ni]);
    }

    float bs[4];
#pragma unroll
    for (int ni = 0; ni < 4; ++ni) bs[ni] = bias[n0 + wn*64 + 16*ni + l15];
#pragma unroll
    for (int mi = 0; mi < 4; ++mi) {
        const int row = m0 + wm*64 + 16*mi + 4*hh;
#pragma unroll
        for (int r = 0; r < 4; ++r) {
            float* o = out + (size_t)(row + r) * 1024 + n0 + wn*64;
#pragma unroll
            for (int ni = 0; ni < 4; ++ni)
                o[16*ni + l15] = acc[mi][ni][r] + bs[ni];
        }
    }
}

// ------------------------------------------------------------ launch ------
extern "C" void kernel_launch(void* const* d_in, const int* in_sizes, int n_in,
                              void* d_out, int out_size, void* d_ws, size_t ws_size,
                              hipStream_t stream) {
    const float* q    = (const float*)d_in[0];
    const float* k    = (const float*)d_in[1];
    const float* v    = (const float*)d_in[2];
    const float* W    = (const float*)d_in[3];
    const float* bias = (const float*)d_in[4];
    const float* proj = (const float*)d_in[5];
    float* out = (float*)d_out;

    char* ws = (char*)d_ws;
    unsigned short* attn  = (unsigned short*)(ws);              // 33,554,432 B
    float*          ctxp  = (float*)(ws + 33554432);            // 16,777,216 B
    unsigned short* ctxT  = (unsigned short*)(ws + 50331648);   //  2,097,152 B
    unsigned short* Wb    = (unsigned short*)(ws + 52428800);   //  2,097,152 B
    float*          ksum  = (float*)(ws + 54525952);            //     65,536 B
    float*          ksump = (float*)(ws + 54591488);            //    262,144 B
    unsigned short* projs = (unsigned short*)(ws + 54853632);   //     32,768 B

    k_prep<<<dim3(4096), dim3(256), 0, stream>>>(W, proj, Wb, projs);
    k_ctx<<<dim3(256), dim3(256), 0, stream>>>(k, v, projs, ctxp, ksump);
    k_reduce<<<dim3(64), dim3(256), 0, stream>>>(ctxp, ksump, ctxT, ksum);
    k_qout<<<dim3(1024), dim3(256), 0, stream>>>(q, projs, ctxT, ksum, attn);
    k_linear<<<dim3(1024), dim3(256), 0, stream>>>(attn, Wb, bias, out);
}